// Round 8
// baseline (56.268 us; speedup 1.0000x reference)
//
#include <hip/hip_runtime.h>
#include <math.h>

#define LDIM 64
#define QT2 32   // queries per tile
#define QW 8     // queries per wave
#define LOG2E 1.4426950408889634f

static __device__ __forceinline__ float fast_exp2(float x) {
#if __has_builtin(__builtin_amdgcn_exp2f)
    return __builtin_amdgcn_exp2f(x);
#else
    return exp2f(x);
#endif
}

static __device__ __forceinline__ float4 ld4(const float* p) {
    return *(const float4*)p;
}

// K1: V[o][l] = bv[l] + h_obs[o]·Wv[:,l]   and zero acc/den/cnt.
__global__ __launch_bounds__(256) void gano_pre(
    const float* __restrict__ h_obs, const float* __restrict__ Wv,
    const float* __restrict__ bv,
    float* __restrict__ V, float* __restrict__ zeroRegion,
    int No, int NoA, int zn)
{
    const int gid = blockIdx.x * blockDim.x + threadIdx.x;
    if (gid >= NoA * LDIM) return;
    const int o = gid >> 6, l = gid & 63;
    float vv = 0.0f;
    if (o < No) {
        vv = bv[l];
        #pragma unroll 16
        for (int k = 0; k < LDIM; ++k)
            vv = fmaf(h_obs[o * LDIM + k], Wv[k * LDIM + l], vv);
    }
    V[gid] = vv;
    if (gid < zn) zeroRegion[gid] = 0.0f;
}

// K2: one (64-obs chunk, 32-query tile) per block. In-block staging of the
// B-chunk and query-side preacts; logits (lane=obs, 8 q/wave); no-max e;
// PV (lane=l, e via wave-private LDS broadcast); atomicAdd acc/den; the
// LAST block per tile (completion counter) normalizes and writes out.
__global__ __launch_bounds__(256) void gano_fused(
    const float* __restrict__ pos_obs, const float* __restrict__ pos_query,
    const float* __restrict__ W1, const float* __restrict__ b1,
    const float* __restrict__ W2, const float* __restrict__ V,
    const int* __restrict__ obs_mask, const int* __restrict__ obs_batch,
    const int* __restrict__ query_batch,
    float* __restrict__ acc, float* __restrict__ den, int* __restrict__ cnt,
    float* __restrict__ out, int No, int Nq, int nC)
{
    const int c   = blockIdx.x;
    const int t   = blockIdx.y;
    const int q0  = t * QT2;
    const int tid = threadIdx.x, lane = tid & 63, wid = tid >> 6;

    const int t_lo = query_batch[q0];
    const int t_hi = query_batch[min(q0 + QT2 - 1, Nq - 1)];

    // chunk-granular active interval [cs, ce]; expected = its size.
    // Active test and counter use the SAME interval -> always consistent.
    int lo = 0, hi = nC;
    while (lo < hi) { int mid = (lo + hi) >> 1;
        if (obs_batch[min(mid * 64 + 63, No - 1)] < t_lo) lo = mid + 1; else hi = mid; }
    const int cs = lo;
    lo = 0; hi = nC;
    while (lo < hi) { int mid = (lo + hi) >> 1;
        if (obs_batch[mid * 64] <= t_hi) lo = mid + 1; else hi = mid; }
    const int ce = lo - 1;
    const int expected = (ce >= cs) ? (ce - cs + 1) : 0;
    const bool active = (c >= cs) & (c <= ce);

    if (!active) {
        if (c == 0 && expected == 0) {   // tile with no obs at all -> zeros
            for (int i = tid; i < QT2 * LDIM; i += 256) {
                const int q = q0 + (i >> 6);
                if (q < Nq) out[(size_t)q * LDIM + (i & 63)] = 0.0f;
            }
        }
        return;
    }

    __shared__ float4 B4[16][64];       // [g][o] obs-side preact chunk
    __shared__ float4 a4[QT2][16];      // [q][g] query-side preact
    __shared__ float4 w2_4[16];         // W2 * log2e
    __shared__ float4 qp4[QT2];         // (x,y,z, batch+1)
    __shared__ float  e_lds[QT2][LDIM]; // wave-private rows
    __shared__ int    sLast;

    // ---- staging ----
    if (tid < QT2) {
        const int q = min(q0 + tid, Nq - 1);
        qp4[tid] = make_float4(pos_query[q*3+0], pos_query[q*3+1], pos_query[q*3+2],
                               (float)(query_batch[q] + 1));
    }
    if (tid < 16) {
        const float4 w = ld4(W2 + 4 * tid);
        w2_4[tid] = make_float4(w.x * LOG2E, w.y * LOG2E, w.z * LOG2E, w.w * LOG2E);
    }
    for (int i = tid; i < QT2 * 16; i += 256) {
        const int q = i >> 4, g = i & 15;
        const int qq = min(q0 + q, Nq - 1);
        const float px = pos_query[qq*3+0], py = pos_query[qq*3+1], pz = pos_query[qq*3+2];
        const float4 u0 = ld4(W1 + 0*LDIM + 4*g), u6 = ld4(W1 + 6*LDIM + 4*g);
        const float4 u1 = ld4(W1 + 1*LDIM + 4*g), u7 = ld4(W1 + 7*LDIM + 4*g);
        const float4 u2 = ld4(W1 + 2*LDIM + 4*g), u8 = ld4(W1 + 8*LDIM + 4*g);
        float4 r;
        r.x = fmaf(px, u0.x+u6.x, fmaf(py, u1.x+u7.x, pz*(u2.x+u8.x)));
        r.y = fmaf(px, u0.y+u6.y, fmaf(py, u1.y+u7.y, pz*(u2.y+u8.y)));
        r.z = fmaf(px, u0.z+u6.z, fmaf(py, u1.z+u7.z, pz*(u2.z+u8.z)));
        r.w = fmaf(px, u0.w+u6.w, fmaf(py, u1.w+u7.w, pz*(u2.w+u8.w)));
        a4[q][g] = r;
    }
    // obs chunk: this lane's pos/mask (reused in the mask phase below)
    const int oo = (c << 6) + lane;
    float px = 0.f, py = 0.f, pz = 0.f, pcode = 0.f;
    if (oo < No) {
        px = pos_obs[oo*3+0]; py = pos_obs[oo*3+1]; pz = pos_obs[oo*3+2];
        pcode = obs_mask[oo] ? (float)(obs_batch[oo] + 1) : 0.0f;
    }
    #pragma unroll
    for (int k = 0; k < 4; ++k) {
        const int g = ((tid >> 6) + k * 4) & 15;
        const float4 b0 = ld4(b1 + 4*g);
        const float4 u3 = ld4(W1 + 3*LDIM + 4*g), u6 = ld4(W1 + 6*LDIM + 4*g);
        const float4 u4 = ld4(W1 + 4*LDIM + 4*g), u7 = ld4(W1 + 7*LDIM + 4*g);
        const float4 u5 = ld4(W1 + 5*LDIM + 4*g), u8 = ld4(W1 + 8*LDIM + 4*g);
        float4 r;
        r.x = fmaf(px, u3.x-u6.x, fmaf(py, u4.x-u7.x, fmaf(pz, u5.x-u8.x, b0.x)));
        r.y = fmaf(px, u3.y-u6.y, fmaf(py, u4.y-u7.y, fmaf(pz, u5.y-u8.y, b0.y)));
        r.z = fmaf(px, u3.z-u6.z, fmaf(py, u4.z-u7.z, fmaf(pz, u5.z-u8.z, b0.z)));
        r.w = fmaf(px, u3.w-u6.w, fmaf(py, u4.w-u7.w, fmaf(pz, u5.w-u8.w, b0.w)));
        B4[g][lane] = r;
    }
    __syncthreads();

    // ---- logits: lane = obs, 8 queries per wave ----
    float lgq[QW];
    #pragma unroll
    for (int j = 0; j < QW; ++j) lgq[j] = 0.0f;
    #pragma unroll
    for (int g = 0; g < 16; ++g) {
        const float4 Bv = B4[g][lane];
        const float4 w  = w2_4[g];
        #pragma unroll
        for (int j = 0; j < QW; ++j) {
            const float4 a = a4[wid * QW + j][g];
            lgq[j] = fmaf(fmaxf(a.x + Bv.x, 0.f), w.x, lgq[j]);
            lgq[j] = fmaf(fmaxf(a.y + Bv.y, 0.f), w.y, lgq[j]);
            lgq[j] = fmaf(fmaxf(a.z + Bv.z, 0.f), w.z, lgq[j]);
            lgq[j] = fmaf(fmaxf(a.w + Bv.w, 0.f), w.w, lgq[j]);
        }
    }

    // ---- mask + direct exp2 (no-max softmax, validated R6/R7) ----
    float ds[QW];
    #pragma unroll
    for (int j = 0; j < QW; ++j) {
        const float4 qp = qp4[wid * QW + j];
        const float dx = qp.x - px, dy = qp.y - py, dz = qp.z - pz;
        const float d2 = fmaf(dz, dz, fmaf(dy, dy, dx * dx));
        const bool valid = (pcode == qp.w) & (d2 <= 1.0f);
        const float e = valid ? fast_exp2(lgq[j]) : 0.0f;
        e_lds[wid * QW + j][lane] = e;
        ds[j] = e;
    }
    #pragma unroll
    for (int msk = 32; msk; msk >>= 1) {
        #pragma unroll
        for (int j = 0; j < QW; ++j) ds[j] += __shfl_xor(ds[j], msk, 64);
    }
    if (lane == 0) {
        #pragma unroll
        for (int j = 0; j < QW; ++j) atomicAdd(&den[q0 + wid * QW + j], ds[j]);
    }

    // ---- PV: lane = hidden dim ----
    const float* Vc = V + ((size_t)c << 12) + lane;
    float pacc[QW];
    #pragma unroll
    for (int j = 0; j < QW; ++j) pacc[j] = 0.0f;
    for (int o2 = 0; o2 < LDIM; o2 += 4) {
        const float v0 = Vc[(o2 + 0) << 6];
        const float v1 = Vc[(o2 + 1) << 6];
        const float v2 = Vc[(o2 + 2) << 6];
        const float v3 = Vc[(o2 + 3) << 6];
        #pragma unroll
        for (int j = 0; j < QW; ++j) {
            const float4 e = *(const float4*)&e_lds[wid * QW + j][o2];
            pacc[j] = fmaf(e.x, v0, pacc[j]);
            pacc[j] = fmaf(e.y, v1, pacc[j]);
            pacc[j] = fmaf(e.z, v2, pacc[j]);
            pacc[j] = fmaf(e.w, v3, pacc[j]);
        }
    }
    #pragma unroll
    for (int j = 0; j < QW; ++j)
        atomicAdd(&acc[(size_t)(q0 + wid * QW + j) * LDIM + lane], pacc[j]);

    // ---- completion counter: last block of this tile normalizes ----
    __threadfence();
    __syncthreads();
    if (tid == 0) {
        const int old = __hip_atomic_fetch_add(&cnt[t], 1, __ATOMIC_ACQ_REL,
                                               __HIP_MEMORY_SCOPE_AGENT);
        sLast = (old == expected - 1);
    }
    __syncthreads();
    if (sLast) {
        for (int i = tid; i < QT2 * LDIM; i += 256) {
            const int q = q0 + (i >> 6);
            if (q < Nq) {
                const float D = __hip_atomic_load(&den[q], __ATOMIC_RELAXED,
                                                  __HIP_MEMORY_SCOPE_AGENT);
                const float Av = __hip_atomic_load(&acc[(size_t)q * LDIM + (i & 63)],
                                                   __ATOMIC_RELAXED,
                                                   __HIP_MEMORY_SCOPE_AGENT);
                out[(size_t)q * LDIM + (i & 63)] = Av / fmaxf(D, 1e-30f);
            }
        }
    }
}

extern "C" void kernel_launch(void* const* d_in, const int* in_sizes, int n_in,
                              void* d_out, int out_size, void* d_ws, size_t ws_size,
                              hipStream_t stream) {
    const float* h_obs     = (const float*)d_in[0];
    const float* pos_obs   = (const float*)d_in[1];
    const float* pos_query = (const float*)d_in[2];
    const float* W1        = (const float*)d_in[3];
    const float* b1        = (const float*)d_in[4];
    const float* W2        = (const float*)d_in[5];
    // d_in[6] = b2: constant shift, cancels in softmax -> unused
    const float* Wv        = (const float*)d_in[7];
    const float* bv        = (const float*)d_in[8];
    const int* obs_mask    = (const int*)d_in[9];
    const int* obs_batch   = (const int*)d_in[10];
    const int* query_batch = (const int*)d_in[11];

    const int No     = in_sizes[1] / 3;
    const int Nq     = in_sizes[2] / 3;
    const int NoA    = (No + 63) & ~63;
    const int nC     = NoA / 64;
    const int nTiles = (Nq + QT2 - 1) / QT2;

    // ws layout: V | acc | den | cnt   (~0.8 MB)
    float* V   = (float*)d_ws;                 // NoA*64 f
    float* acc = V + (size_t)NoA * LDIM;       // Nq*64 f  (zeroed)
    float* den = acc + (size_t)Nq * LDIM;      // Nq f     (zeroed)
    int*   cnt = (int*)(den + Nq);             // nTiles i (zeroed)
    const int zn = Nq * (LDIM + 1) + nTiles;

    gano_pre<<<(NoA * LDIM + 255) / 256, 256, 0, stream>>>(
        h_obs, Wv, bv, V, acc, No, NoA, zn);

    dim3 g2(nC, nTiles);
    gano_fused<<<g2, 256, 0, stream>>>(
        pos_obs, pos_query, W1, b1, W2, V,
        obs_mask, obs_batch, query_batch,
        acc, den, cnt, (float*)d_out, No, Nq, nC);
}

// Round 9
// 31.916 us; speedup vs baseline: 1.7630x; 1.7630x over previous
//
#include <hip/hip_runtime.h>
#include <math.h>

#define LDIM 64
#define QT2 32   // queries per tile
#define QW 8     // queries per wave
#define LOG2E 1.4426950408889634f

static __device__ __forceinline__ float fast_exp2(float x) {
#if __has_builtin(__builtin_amdgcn_exp2f)
    return __builtin_amdgcn_exp2f(x);
#else
    return exp2f(x);
#endif
}

static __device__ __forceinline__ float4 ld4(const float* p) {
    return *(const float4*)p;
}

// K1: one (64-obs chunk, 32-query tile) per block. In-block staging of the
// obs-side preact chunk B4 and query-side preacts a4; logits (lane=obs,
// 8 q/wave); no-max e (validated R6-R8); PV accumulates h_obs DIRECTLY
// (linearity: weights@(h@Wv+bv) = (weights@h)@Wv + bv); plain atomicAdd
// to acc/den — NO fences, NO acq/rel (R8 lesson: device fences cost ~60us).
__global__ __launch_bounds__(256) void gano_accum(
    const float* __restrict__ h_obs,
    const float* __restrict__ pos_obs, const float* __restrict__ pos_query,
    const float* __restrict__ W1, const float* __restrict__ b1,
    const float* __restrict__ W2,
    const int* __restrict__ obs_mask, const int* __restrict__ obs_batch,
    const int* __restrict__ query_batch,
    float* __restrict__ acc, float* __restrict__ den,
    int No, int Nq)
{
    const int c   = blockIdx.x;
    const int q0  = blockIdx.y * QT2;
    const int tid = threadIdx.x, lane = tid & 63, wid = tid >> 6;

    if ((c << 6) >= No) return;
    // batch-span intersection early-exit (both arrays sorted)
    const int c_lo = obs_batch[c << 6];
    const int c_hi = obs_batch[min((c << 6) + 63, No - 1)];
    if (c_lo > query_batch[min(q0 + QT2 - 1, Nq - 1)] || c_hi < query_batch[q0]) return;

    __shared__ float4 B4[16][64];       // [g][o] obs-side preact chunk
    __shared__ float4 a4[QT2][16];      // [q][g] query-side preact
    __shared__ float4 w2_4[16];         // W2 * log2e
    __shared__ float4 qp4[QT2];         // (x,y,z, batch+1)
    __shared__ float  e_lds[QT2][LDIM]; // wave-private rows

    // ---- staging ----
    if (tid < QT2) {
        const int q = min(q0 + tid, Nq - 1);
        qp4[tid] = make_float4(pos_query[q*3+0], pos_query[q*3+1], pos_query[q*3+2],
                               (float)(query_batch[q] + 1));
    }
    if (tid < 16) {
        const float4 w = ld4(W2 + 4 * tid);
        w2_4[tid] = make_float4(w.x * LOG2E, w.y * LOG2E, w.z * LOG2E, w.w * LOG2E);
    }
    for (int i = tid; i < QT2 * 16; i += 256) {
        const int q = i >> 4, g = i & 15;
        const int qq = min(q0 + q, Nq - 1);
        const float px = pos_query[qq*3+0], py = pos_query[qq*3+1], pz = pos_query[qq*3+2];
        const float4 u0 = ld4(W1 + 0*LDIM + 4*g), u6 = ld4(W1 + 6*LDIM + 4*g);
        const float4 u1 = ld4(W1 + 1*LDIM + 4*g), u7 = ld4(W1 + 7*LDIM + 4*g);
        const float4 u2 = ld4(W1 + 2*LDIM + 4*g), u8 = ld4(W1 + 8*LDIM + 4*g);
        float4 r;
        r.x = fmaf(px, u0.x+u6.x, fmaf(py, u1.x+u7.x, pz*(u2.x+u8.x)));
        r.y = fmaf(px, u0.y+u6.y, fmaf(py, u1.y+u7.y, pz*(u2.y+u8.y)));
        r.z = fmaf(px, u0.z+u6.z, fmaf(py, u1.z+u7.z, pz*(u2.z+u8.z)));
        r.w = fmaf(px, u0.w+u6.w, fmaf(py, u1.w+u7.w, pz*(u2.w+u8.w)));
        a4[q][g] = r;
    }
    // obs chunk: this lane's pos/mask (reused in the mask phase)
    const int oo = (c << 6) + lane;
    float px = 0.f, py = 0.f, pz = 0.f, pcode = 0.f;
    if (oo < No) {
        px = pos_obs[oo*3+0]; py = pos_obs[oo*3+1]; pz = pos_obs[oo*3+2];
        pcode = obs_mask[oo] ? (float)(obs_batch[oo] + 1) : 0.0f;
    }
    #pragma unroll
    for (int k = 0; k < 4; ++k) {
        const int g = (wid + k * 4) & 15;
        const float4 b0 = ld4(b1 + 4*g);
        const float4 u3 = ld4(W1 + 3*LDIM + 4*g), u6 = ld4(W1 + 6*LDIM + 4*g);
        const float4 u4 = ld4(W1 + 4*LDIM + 4*g), u7 = ld4(W1 + 7*LDIM + 4*g);
        const float4 u5 = ld4(W1 + 5*LDIM + 4*g), u8 = ld4(W1 + 8*LDIM + 4*g);
        float4 r;
        r.x = fmaf(px, u3.x-u6.x, fmaf(py, u4.x-u7.x, fmaf(pz, u5.x-u8.x, b0.x)));
        r.y = fmaf(px, u3.y-u6.y, fmaf(py, u4.y-u7.y, fmaf(pz, u5.y-u8.y, b0.y)));
        r.z = fmaf(px, u3.z-u6.z, fmaf(py, u4.z-u7.z, fmaf(pz, u5.z-u8.z, b0.z)));
        r.w = fmaf(px, u3.w-u6.w, fmaf(py, u4.w-u7.w, fmaf(pz, u5.w-u8.w, b0.w)));
        B4[g][lane] = r;
    }
    __syncthreads();

    // ---- logits: lane = obs, 8 queries per wave ----
    float lgq[QW];
    #pragma unroll
    for (int j = 0; j < QW; ++j) lgq[j] = 0.0f;
    #pragma unroll
    for (int g = 0; g < 16; ++g) {
        const float4 Bv = B4[g][lane];
        const float4 w  = w2_4[g];
        #pragma unroll
        for (int j = 0; j < QW; ++j) {
            const float4 a = a4[wid * QW + j][g];
            lgq[j] = fmaf(fmaxf(a.x + Bv.x, 0.f), w.x, lgq[j]);
            lgq[j] = fmaf(fmaxf(a.y + Bv.y, 0.f), w.y, lgq[j]);
            lgq[j] = fmaf(fmaxf(a.z + Bv.z, 0.f), w.z, lgq[j]);
            lgq[j] = fmaf(fmaxf(a.w + Bv.w, 0.f), w.w, lgq[j]);
        }
    }

    // ---- mask + direct exp2 (no-max softmax) ----
    float ds[QW];
    #pragma unroll
    for (int j = 0; j < QW; ++j) {
        const float4 qp = qp4[wid * QW + j];
        const float dx = qp.x - px, dy = qp.y - py, dz = qp.z - pz;
        const float d2 = fmaf(dz, dz, fmaf(dy, dy, dx * dx));
        const bool valid = (pcode == qp.w) & (d2 <= 1.0f);
        const float e = valid ? fast_exp2(lgq[j]) : 0.0f;
        e_lds[wid * QW + j][lane] = e;
        ds[j] = e;
    }
    #pragma unroll
    for (int msk = 32; msk; msk >>= 1) {
        #pragma unroll
        for (int j = 0; j < QW; ++j) ds[j] += __shfl_xor(ds[j], msk, 64);
    }
    if (lane == 0) {
        #pragma unroll
        for (int j = 0; j < QW; ++j) atomicAdd(&den[q0 + wid * QW + j], ds[j]);
    }

    // ---- PV: lane = hidden-input dim k; accumulate e * h_obs[o][k] ----
    float pacc[QW];
    #pragma unroll
    for (int j = 0; j < QW; ++j) pacc[j] = 0.0f;
    const float* Hc = h_obs + ((size_t)c << 12) + lane;
    if ((c << 6) + 64 <= No) {
        for (int o2 = 0; o2 < LDIM; o2 += 4) {
            const float v0 = Hc[(o2 + 0) << 6];
            const float v1 = Hc[(o2 + 1) << 6];
            const float v2 = Hc[(o2 + 2) << 6];
            const float v3 = Hc[(o2 + 3) << 6];
            #pragma unroll
            for (int j = 0; j < QW; ++j) {
                const float4 e = *(const float4*)&e_lds[wid * QW + j][o2];
                pacc[j] = fmaf(e.x, v0, pacc[j]);
                pacc[j] = fmaf(e.y, v1, pacc[j]);
                pacc[j] = fmaf(e.z, v2, pacc[j]);
                pacc[j] = fmaf(e.w, v3, pacc[j]);
            }
        }
    } else {  // tail chunk: clamp rows (e is 0 there anyway)
        for (int o2 = 0; o2 < LDIM; ++o2) {
            const int orow = min((c << 6) + o2, No - 1);
            const float v0 = h_obs[((size_t)orow << 6) + lane];
            #pragma unroll
            for (int j = 0; j < QW; ++j)
                pacc[j] = fmaf(e_lds[wid * QW + j][o2], v0, pacc[j]);
        }
    }
    #pragma unroll
    for (int j = 0; j < QW; ++j)
        atomicAdd(&acc[(size_t)(q0 + wid * QW + j) * LDIM + lane], pacc[j]);
}

// K2: normalize + Wv epilogue + bv.  out[q] = (acc[q]/D) @ Wv + bv, or 0 if D==0.
// 4 waves x 2 queries per block; r broadcast via wave-private LDS.
__global__ __launch_bounds__(256) void gano_norm(
    const float* __restrict__ acc, const float* __restrict__ den,
    const float* __restrict__ Wv, const float* __restrict__ bv,
    float* __restrict__ out, int Nq)
{
    const int tid = threadIdx.x, lane = tid & 63, wid = tid >> 6;
    const int q0 = blockIdx.x * 8 + wid * 2;
    if (q0 >= Nq) return;

    __shared__ float r_lds[4][2][LDIM];

    const float D0 = den[q0];
    const float D1 = (q0 + 1 < Nq) ? den[q0 + 1] : 0.0f;
    const float rd0 = (D0 > 0.0f) ? 1.0f / D0 : 0.0f;
    const float rd1 = (D1 > 0.0f) ? 1.0f / D1 : 0.0f;
    r_lds[wid][0][lane] = acc[(size_t)q0 * LDIM + lane] * rd0;
    r_lds[wid][1][lane] = (q0 + 1 < Nq) ? acc[(size_t)(q0 + 1) * LDIM + lane] * rd1 : 0.0f;
    // wave-private: no barrier needed
    float o0 = 0.f, o1 = 0.f;
    #pragma unroll 8
    for (int k = 0; k < LDIM; ++k) {
        const float w = Wv[(k << 6) + lane];
        o0 = fmaf(r_lds[wid][0][k], w, o0);
        o1 = fmaf(r_lds[wid][1][k], w, o1);
    }
    const float b = bv[lane];
    out[(size_t)q0 * LDIM + lane] = (D0 > 0.0f) ? o0 + b : 0.0f;
    if (q0 + 1 < Nq)
        out[(size_t)(q0 + 1) * LDIM + lane] = (D1 > 0.0f) ? o1 + b : 0.0f;
}

extern "C" void kernel_launch(void* const* d_in, const int* in_sizes, int n_in,
                              void* d_out, int out_size, void* d_ws, size_t ws_size,
                              hipStream_t stream) {
    const float* h_obs     = (const float*)d_in[0];
    const float* pos_obs   = (const float*)d_in[1];
    const float* pos_query = (const float*)d_in[2];
    const float* W1        = (const float*)d_in[3];
    const float* b1        = (const float*)d_in[4];
    const float* W2        = (const float*)d_in[5];
    // d_in[6] = b2: constant shift, cancels in softmax -> unused
    const float* Wv        = (const float*)d_in[7];
    const float* bv        = (const float*)d_in[8];
    const int* obs_mask    = (const int*)d_in[9];
    const int* obs_batch   = (const int*)d_in[10];
    const int* query_batch = (const int*)d_in[11];

    const int No     = in_sizes[1] / 3;
    const int Nq     = in_sizes[2] / 3;
    const int NoA    = (No + 63) & ~63;
    const int nC     = NoA / 64;
    const int nTiles = (Nq + QT2 - 1) / QT2;

    // ws layout: acc (Nq*64) | den (Nq)
    float* acc = (float*)d_ws;
    float* den = acc + (size_t)Nq * LDIM;

    hipMemsetAsync(acc, 0, (size_t)Nq * (LDIM + 1) * sizeof(float), stream);

    dim3 g1(nC, nTiles);
    gano_accum<<<g1, 256, 0, stream>>>(
        h_obs, pos_obs, pos_query, W1, b1, W2,
        obs_mask, obs_batch, query_batch,
        acc, den, No, Nq);

    gano_norm<<<(Nq + 7) / 8, 256, 0, stream>>>(acc, den, Wv, bv, (float*)d_out, Nq);
}